// Round 1
// baseline (1778.778 us; speedup 1.0000x reference)
//
#include <hip/hip_runtime.h>
#include <hip/hip_bf16.h>

#define BATCH 16
#define NPTS  4096
#define NSAMP 1024   // S = N * 0.25
#define KNB   32     // nsample
#define DFEAT 64

// ---------------------------------------------------------------------------
// Kernel 1: farthest point sampling. One block per batch.
// Writes fps_idx [B,S] (ws) and new_xyz_out [B,3,S] (d_out part 0).
// ---------------------------------------------------------------------------
__global__ __launch_bounds__(256) void fps_kernel(const float* __restrict__ xyz,
                                                  int* __restrict__ fps_idx,
                                                  float* __restrict__ out_xyz) {
    const int b   = blockIdx.x;
    const int tid = threadIdx.x;
    const int lane = tid & 63;
    const int wid  = tid >> 6;

    __shared__ float sx[NPTS], sy[NPTS], sz[NPTS];
    __shared__ float rbv[4];
    __shared__ int   rbi[4];
    __shared__ int   scur;

    const float* base = xyz + (size_t)b * NPTS * 3;
    for (int i = tid; i < NPTS; i += 256) {
        sx[i] = base[i * 3 + 0];
        sy[i] = base[i * 3 + 1];
        sz[i] = base[i * 3 + 2];
    }
    __syncthreads();

    float md[16];
#pragma unroll
    for (int j = 0; j < 16; j++) md[j] = 1e10f;

    int cur = 0;
    if (tid == 0) {
        fps_idx[b * NSAMP + 0] = 0;
        out_xyz[(size_t)b * 3 * NSAMP + 0 * NSAMP + 0] = sx[0];
        out_xyz[(size_t)b * 3 * NSAMP + 1 * NSAMP + 0] = sy[0];
        out_xyz[(size_t)b * 3 * NSAMP + 2 * NSAMP + 0] = sz[0];
    }

    for (int s = 1; s < NSAMP; s++) {
        const float cx = sx[cur], cy = sy[cur], cz = sz[cur];
        float best = -1.0f;
        int   bi   = 0;
#pragma unroll
        for (int j = 0; j < 16; j++) {
            const int p = j * 256 + tid;
            const float dx = sx[p] - cx;
            const float dy = sy[p] - cy;
            const float dz = sz[p] - cz;
            // match reference rounding: squares and sums, no fma contraction
            const float d = __fadd_rn(__fadd_rn(__fmul_rn(dx, dx), __fmul_rn(dy, dy)),
                                      __fmul_rn(dz, dz));
            const float m = fminf(md[j], d);
            md[j] = m;
            if (m > best) { best = m; bi = p; }   // strict > keeps lowest index
        }
        // wave butterfly reduce, max value / lowest index on ties
#pragma unroll
        for (int off = 32; off > 0; off >>= 1) {
            const float ov = __shfl_xor(best, off);
            const int   oi = __shfl_xor(bi, off);
            if (ov > best || (ov == best && oi < bi)) { best = ov; bi = oi; }
        }
        if (lane == 0) { rbv[wid] = best; rbi[wid] = bi; }
        __syncthreads();
        if (tid == 0) {
            float bv  = rbv[0];
            int   bix = rbi[0];
#pragma unroll
            for (int w = 1; w < 4; w++) {
                const float v  = rbv[w];
                const int   i2 = rbi[w];
                if (v > bv || (v == bv && i2 < bix)) { bv = v; bix = i2; }
            }
            scur = bix;
            fps_idx[b * NSAMP + s] = bix;
            out_xyz[(size_t)b * 3 * NSAMP + 0 * NSAMP + s] = sx[bix];
            out_xyz[(size_t)b * 3 * NSAMP + 1 * NSAMP + s] = sy[bix];
            out_xyz[(size_t)b * 3 * NSAMP + 2 * NSAMP + s] = sz[bix];
        }
        __syncthreads();
        cur = scur;
    }
}

// ---------------------------------------------------------------------------
// Kernel 2: ball query. One wave (64 lanes) per query point.
// grp [B,S,32] int32: first 32 indices (ascending) with sqd <= r^2,
// remainder filled with the first found index.
// ---------------------------------------------------------------------------
__global__ __launch_bounds__(256) void ballq_kernel(const float* __restrict__ xyz,
                                                    const int* __restrict__ fps_idx,
                                                    int* __restrict__ grp) {
    const int q    = blockIdx.x * 4 + (threadIdx.x >> 6);
    const int lane = threadIdx.x & 63;
    const int b    = q >> 10;       // / NSAMP
    const int c    = fps_idx[q];

    const float* base = xyz + (size_t)b * NPTS * 3;
    const float cx = base[c * 3 + 0];
    const float cy = base[c * 3 + 1];
    const float cz = base[c * 3 + 2];
    const float r2 = 0.04f;         // f32(0.2*0.2), matches jax weak-type conversion

    int* g = grp + (size_t)q * KNB;
    int cnt = 0;
    int firstCand = 0x7fffffff;

    for (int bp = 0; bp < NPTS && cnt < KNB; bp += 64) {
        const int p = bp + lane;
        const float dx = base[p * 3 + 0] - cx;
        const float dy = base[p * 3 + 1] - cy;
        const float dz = base[p * 3 + 2] - cz;
        const float d = __fadd_rn(__fadd_rn(__fmul_rn(dx, dx), __fmul_rn(dy, dy)),
                                  __fmul_rn(dz, dz));
        const bool ok = !(d > r2);
        const unsigned long long m = __ballot(ok);
        const int rank = cnt + (int)__popcll(m & ((1ull << lane) - 1ull));
        if (ok && rank < KNB) g[rank] = p;
        if (ok && rank == 0) firstCand = p;
        cnt += (int)__popcll(m);
    }

    // fill remainder with first index (cnt >= 1 always: center point itself)
    const int found = cnt < KNB ? cnt : KNB;
    if (found < KNB) {
#pragma unroll
        for (int off = 32; off > 0; off >>= 1) {
            const int o = __shfl_xor(firstCand, off);
            firstCand = o < firstCand ? o : firstCand;
        }
        for (int r = found + lane; r < KNB; r += 64) g[r] = firstCand;
    }
}

// ---------------------------------------------------------------------------
// Kernel 3: gather + MLP(64->64 relu, 64->128 relu) + max over 32 samples.
// One wave per query; lane = channel. W1 row + 2 W2 rows in registers.
// Writes new_points_out [B,128,S] (d_out part 1).
// ---------------------------------------------------------------------------
__global__ __launch_bounds__(256) void mlp_kernel(const float* __restrict__ features,
                                                  const int* __restrict__ grp,
                                                  const float* __restrict__ W1,
                                                  const float* __restrict__ b1,
                                                  const float* __restrict__ W2,
                                                  const float* __restrict__ b2,
                                                  float* __restrict__ out_pts) {
    const int wid  = threadIdx.x >> 6;
    const int lane = threadIdx.x & 63;
    const int q    = blockIdx.x * 4 + wid;
    const int b    = q >> 10;
    const int s    = q & 1023;

    __shared__ float xls[4][KNB][DFEAT];   // 32 KB
    __shared__ float h1s[4][DFEAT];        // 1 KB

    // weights -> registers
    float w1r[64], w2ra[64], w2rb[64];
    {
        const float4* W1v = (const float4*)(W1 + (size_t)lane * 64);
        const float4* W2a = (const float4*)(W2 + (size_t)lane * 64);
        const float4* W2b = (const float4*)(W2 + (size_t)(lane + 64) * 64);
#pragma unroll
        for (int i = 0; i < 16; i++) {
            float4 v = W1v[i];
            w1r[4 * i] = v.x; w1r[4 * i + 1] = v.y; w1r[4 * i + 2] = v.z; w1r[4 * i + 3] = v.w;
            v = W2a[i];
            w2ra[4 * i] = v.x; w2ra[4 * i + 1] = v.y; w2ra[4 * i + 2] = v.z; w2ra[4 * i + 3] = v.w;
            v = W2b[i];
            w2rb[4 * i] = v.x; w2rb[4 * i + 1] = v.y; w2rb[4 * i + 2] = v.z; w2rb[4 * i + 3] = v.w;
        }
    }
    const float b1r  = b1[lane];
    const float b2ra = b2[lane];
    const float b2rb = b2[lane + 64];

    // gather 32 neighbor feature rows into LDS (coalesced 256B per row)
    int gi = 0;
    if (lane < KNB) gi = grp[(size_t)q * KNB + lane];
    const float* fb = features + (size_t)b * NPTS * DFEAT;
    for (int k = 0; k < KNB; k++) {
        const int idxk = __shfl(gi, k);
        xls[wid][k][lane] = fb[(size_t)idxk * DFEAT + lane];
    }
    __syncthreads();

    float m0 = 0.0f, m1 = 0.0f;   // relu outputs are >= 0, so 0-init is exact
    for (int k = 0; k < KNB; k++) {
        // layer 1: lane computes channel `lane`
        float acc = b1r;
        const float4* xk = (const float4*)xls[wid][k];
#pragma unroll
        for (int i = 0; i < 16; i++) {
            const float4 v = xk[i];
            acc = fmaf(v.x, w1r[4 * i], acc);
            acc = fmaf(v.y, w1r[4 * i + 1], acc);
            acc = fmaf(v.z, w1r[4 * i + 2], acc);
            acc = fmaf(v.w, w1r[4 * i + 3], acc);
        }
        const float h = fmaxf(acc, 0.0f);
        __syncthreads();
        h1s[wid][lane] = h;
        __syncthreads();
        // layer 2: lane computes channels lane and lane+64
        float a0 = b2ra, a1 = b2rb;
        const float4* hv4 = (const float4*)h1s[wid];
#pragma unroll
        for (int i = 0; i < 16; i++) {
            const float4 v = hv4[i];
            a0 = fmaf(v.x, w2ra[4 * i], a0);
            a0 = fmaf(v.y, w2ra[4 * i + 1], a0);
            a0 = fmaf(v.z, w2ra[4 * i + 2], a0);
            a0 = fmaf(v.w, w2ra[4 * i + 3], a0);
            a1 = fmaf(v.x, w2rb[4 * i], a1);
            a1 = fmaf(v.y, w2rb[4 * i + 1], a1);
            a1 = fmaf(v.z, w2rb[4 * i + 2], a1);
            a1 = fmaf(v.w, w2rb[4 * i + 3], a1);
        }
        m0 = fmaxf(m0, fmaxf(a0, 0.0f));
        m1 = fmaxf(m1, fmaxf(a1, 0.0f));
    }

    out_pts[(size_t)b * 128 * NSAMP + (size_t)lane * NSAMP + s]        = m0;
    out_pts[(size_t)b * 128 * NSAMP + (size_t)(lane + 64) * NSAMP + s] = m1;
}

extern "C" void kernel_launch(void* const* d_in, const int* in_sizes, int n_in,
                              void* d_out, int out_size, void* d_ws, size_t ws_size,
                              hipStream_t stream) {
    const float* xyz      = (const float*)d_in[0];
    const float* features = (const float*)d_in[1];
    const float* W1       = (const float*)d_in[2];
    const float* b1       = (const float*)d_in[3];
    const float* W2       = (const float*)d_in[4];
    const float* b2       = (const float*)d_in[5];

    float* out_xyz = (float*)d_out;                                  // [B,3,S]
    float* out_pts = (float*)d_out + (size_t)BATCH * 3 * NSAMP;      // [B,128,S]

    int* fps_idx = (int*)d_ws;                                       // [B,S]
    int* grp     = fps_idx + (size_t)BATCH * NSAMP;                  // [B,S,32]

    fps_kernel<<<BATCH, 256, 0, stream>>>(xyz, fps_idx, out_xyz);
    ballq_kernel<<<BATCH * NSAMP / 4, 256, 0, stream>>>(xyz, fps_idx, grp);
    mlp_kernel<<<BATCH * NSAMP / 4, 256, 0, stream>>>(features, grp, W1, b1, W2, b2, out_pts);
}